// Round 8
// baseline (223651.660 us; speedup 1.0000x reference)
//
#include <hip/hip_runtime.h>
#include <hip/hip_bf16.h>
#include <cstdint>

#define B_ 128
#define T_ 256
#define C_ 512
#define H_ 2048
#define NGROUP 8
#define GSIZE 32        // WGs per set (= per row-group)
#define GPG 4           // groups interleaved per set (latency hiding)
#define NSET 2          // NGROUP / GPG
#define NWG (NSET * GSIZE)   // 64 workgroups
#define NTHR 256
#define M_ 16           // batch rows per group
#define FSTRIDE 16      // flag padding (dwords) -> 64 B per flag
#define RSU1 132        // atile row stride in ull: 264 dw == 8 mod 32 -> uniform banks for b128
#define RSS1 528        // row stride in shorts
// DT = (1/(T-1))/N_SUB = 1/765
#define DT_F 0.0013071895424836601f

typedef __bf16 bf16x8 __attribute__((ext_vector_type(8)));
typedef short s16x8 __attribute__((ext_vector_type(8)));
typedef float f32x4 __attribute__((ext_vector_type(4)));
typedef unsigned long long ull;

// ---------------- workspace layout (bytes) ----------------
enum : size_t {
  OFF_FLAGS = 0,                                    // 8 groups * 32 flags * 64 B
  OFF_W1P = 32768,
  OFF_W2P = OFF_W1P + (size_t)C_ * H_ * 2,          // 2 MB
  OFF_W3P = OFF_W2P + (size_t)H_ * H_ * 2,          // 8 MB
  OFF_U   = OFF_W3P + (size_t)H_ * C_ * 2,          // 2 MB
  OFF_H1  = OFF_U   + (size_t)NGROUP * M_ * C_ * 2, // 128 KB
  OFF_H2  = OFF_H1  + (size_t)NGROUP * M_ * H_ * 2, // 512 KB
  WS_END  = OFF_H2  + (size_t)NGROUP * M_ * H_ * 2  // ~13.4 MB
};

__device__ __forceinline__ bf16x8 ld_frag(const unsigned short* p) {   // cached (weights)
  s16x8 v = *reinterpret_cast<const s16x8*>(p);
  return __builtin_bit_cast(bf16x8, v);
}
__device__ __forceinline__ bf16x8 lds_frag(const unsigned short* p) {  // ds_read_b128
  s16x8 v = *reinterpret_cast<const s16x8*>(p);
  return __builtin_bit_cast(bf16x8, v);
}
__device__ __forceinline__ void st_coh16(unsigned short* p, unsigned short v) {
  __hip_atomic_store(p, v, __ATOMIC_RELAXED, __HIP_MEMORY_SCOPE_AGENT);
}
__device__ __forceinline__ f32x4 mfma16(bf16x8 a, bf16x8 b, f32x4 c) {
  return __builtin_amdgcn_mfma_f32_16x16x32_bf16(a, b, c, 0, 0, 0);
}
__device__ __forceinline__ unsigned short tobf(float f) {
  return __builtin_bit_cast(unsigned short, (__bf16)f);
}
__device__ __forceinline__ float fast_tanh(float v) {
  float e = __expf(2.0f * v);
  return 1.0f - 2.0f / (e + 1.0f);
}

// Intra-staging barrier: drain own LDS ops, raw s_barrier (no vmcnt drain) —
// r7-proven correct & rocprof-neutral-to-positive.
#define LGKM0_BAR() do {                                   \
  asm volatile("s_waitcnt lgkmcnt(0)" ::: "memory");       \
  __builtin_amdgcn_s_barrier();                            \
} while (0)

// ---------------- prologue kernels ----------------
__global__ void init_flags_k(unsigned* f) {
  int i = blockIdx.x * 256 + threadIdx.x;
  if (i < NGROUP * GSIZE * FSTRIDE) f[i] = 0u;
}

// Pack W[K][N] fp32 -> bf16 in MFMA B-fragment order (validated rounds 1-4):
// packed[((nt*(K/32)+kb)*64 + lane)*8 + j] = W[kb*32 + (lane>>4)*8 + j][nt*16 + (lane&15)]
__global__ void swizzle_w_k(const float* __restrict__ W, unsigned short* __restrict__ Wp,
                            int N, int kblog) {
  int idx = blockIdx.x * 256 + threadIdx.x;
  int j = idx & 7;
  int l = (idx >> 3) & 63;
  int rem = idx >> 9;
  int kb = rem & ((1 << kblog) - 1);
  int nt = rem >> kblog;
  int k = kb * 32 + ((l >> 4) << 3) + j;
  int n = (nt << 4) + (l & 15);
  Wp[idx] = tobf(W[(size_t)k * N + n]);
}

// ---------------- split-phase group barrier (32 WGs), MALL padded flags ----
// Baseline-proven primitive, unchanged. One flag array per GROUP; the same
// monotone gen sequence is used for all groups of a set.
__device__ __forceinline__ void bar_arrive(unsigned* gf, int gn, unsigned gen) {
  asm volatile("s_waitcnt vmcnt(0)" ::: "memory");   // own coherent stores drained
  __syncthreads();                                   // all waves drained
  if (threadIdx.x == 0)
    __hip_atomic_store(&gf[gn * FSTRIDE], gen, __ATOMIC_RELAXED, __HIP_MEMORY_SCOPE_AGENT);
}
__device__ __forceinline__ void bar_wait(unsigned* gf, unsigned gen) {
  if (threadIdx.x < GSIZE) {
    while (__hip_atomic_load(&gf[threadIdx.x * FSTRIDE], __ATOMIC_RELAXED,
                             __HIP_MEMORY_SCOPE_AGENT) < gen)
      __builtin_amdgcn_s_sleep(1);
  }
  __syncthreads();
}

// ---------------- staging: batched coherent loads + deferred LDS commit ----------------
__device__ __forceinline__ void issue_u(const ull* __restrict__ g, int tid, ull v[8]) {
  #pragma unroll
  for (int j = 0; j < 8; ++j)     // u is contiguous: 16 rows x 128 ull
    v[j] = __hip_atomic_load(g + j * NTHR + tid, __ATOMIC_RELAXED, __HIP_MEMORY_SCOPE_AGENT);
}
__device__ __forceinline__ void issue_c(const ull* __restrict__ g, int tid, ull v[8]) {
  #pragma unroll
  for (int j = 0; j < 8; ++j) {   // h rows stride 512 ull; chunk = 128 ull of each row
    int i = j * NTHR + tid;
    v[j] = __hip_atomic_load(g + (size_t)(i >> 7) * 512 + (i & 127),
                             __ATOMIC_RELAXED, __HIP_MEMORY_SCOPE_AGENT);
  }
}
__device__ __forceinline__ void commit(ull* __restrict__ lds, int tid, const ull v[8]) {
  #pragma unroll
  for (int j = 0; j < 8; ++j) {
    int i = j * NTHR + tid;
    lds[(i >> 7) * RSU1 + (i & 127)] = v[j];
  }
}

// compile-time-indexed compute macros (keep w2r/w3r register-resident!)
#define L2CHUNK(c, buf) {                                                     \
  const unsigned short* al = (const unsigned short*)atile[buf] + llo * RSS1 + lhi * 8; \
  _Pragma("unroll")                                                           \
  for (int jj = 0; jj < 8; ++jj) {                                            \
    acc0 = mfma16(lds_frag(al + (2 * jj) * 32),     w2r[(c) * 16 + 2 * jj],     acc0); \
    acc1 = mfma16(lds_frag(al + (2 * jj + 1) * 32), w2r[(c) * 16 + 2 * jj + 1], acc1); \
  } }

#define L3CHUNK(c, buf) {                                                     \
  const unsigned short* al = (const unsigned short*)atile[buf] + llo * RSS1 + lhi * 8; \
  _Pragma("unroll")                                                           \
  for (int jj = 0; jj < 2; ++jj) {                                            \
    acc0 = mfma16(lds_frag(al + (wave * 4 + 2 * jj) * 32),     w3r[(c) * 4 + 2 * jj],     acc0); \
    acc1 = mfma16(lds_frag(al + (wave * 4 + 2 * jj + 1) * 32), w3r[(c) * 4 + 2 * jj + 1], acc1); \
  } }

// ---------------- persistent ODE kernel, 4-group interleave ----------------
// 2 sets x 32 WGs; set s serves groups {4s..4s+3} in rotation per layer-step.
// Group X's exchange (store-drain -> flag -> visibility) elapses while the
// other 3 groups compute (~3us slack >= exchange RT) -> waits are satisfied
// polls. Weight registers shared across groups (depend only on gn). All
// communication primitives byte-identical to the proven baseline; generation
// spacing (3 barriers between producer and WAR overwrite) preserved.
__global__ __launch_bounds__(NTHR, 1) void ode_persist_k(
    const float* __restrict__ x, const float* __restrict__ b1,
    const float* __restrict__ b2, const float* __restrict__ b3,
    float* __restrict__ out, unsigned char* __restrict__ ws) {
  const int wg = blockIdx.x, tid = threadIdx.x;
  const int set = wg >> 5, gn = wg & 31;
  const int wave = tid >> 6, lane = tid & 63;
  const int lhi = lane >> 4, llo = lane & 15;

  // per-group pointers (static after unroll)
  unsigned* gf[GPG];
  const ull *ubq[GPG], *h1q[GPG], *h2q[GPG];
  unsigned short *ubs[GPG], *h1s[GPG], *h2s[GPG];
  #pragma unroll
  for (int q = 0; q < GPG; ++q) {
    const int g = set * GPG + q;
    gf[q]  = (unsigned*)(ws + OFF_FLAGS) + g * GSIZE * FSTRIDE;
    ubq[q] = (const ull*)(ws + OFF_U)  + (size_t)g * (M_ * C_ / 4);
    h1q[q] = (const ull*)(ws + OFF_H1) + (size_t)g * (M_ * H_ / 4);
    h2q[q] = (const ull*)(ws + OFF_H2) + (size_t)g * (M_ * H_ / 4);
    ubs[q] = (unsigned short*)(ws + OFF_U)  + (size_t)g * M_ * C_;
    h1s[q] = (unsigned short*)(ws + OFF_H1) + (size_t)g * M_ * H_;
    h2s[q] = (unsigned short*)(ws + OFF_H2) + (size_t)g * M_ * H_;
  }
  const unsigned short* W1p = (const unsigned short*)(ws + OFF_W1P);
  const unsigned short* W2p = (const unsigned short*)(ws + OFF_W2P);
  const unsigned short* W3p = (const unsigned short*)(ws + OFF_W3P);

  __shared__ alignas(16) ull atile[2][M_ * RSU1];   // 33 KB, shared across groups
  __shared__ float red[4][256];                     // 4 KB, shared
  __shared__ float ytile[GPG][256], k1t[GPG][256], k2t[GPG][256], k3t[GPG][256]; // 16 KB

  // weight bases (B-fragment layout) — depend only on gn, shared across groups
  const int n16 = gn * 4 + wave;                    // layers 1,2 column tile
  const unsigned short* bp1 = W1p + (size_t)n16 * 16 * 512 + lane * 8;
  const unsigned short* bp2 = W2p + (size_t)n16 * 64 * 512 + lane * 8;
  const unsigned short* bp3 = W3p + (size_t)gn  * 64 * 512 + lane * 8;

  // ---- register-resident W2 (256 VGPR) and W3 (64 VGPR) slices ----
  bf16x8 w2r[64], w3r[16];
  #pragma unroll
  for (int kb = 0; kb < 64; ++kb) w2r[kb] = ld_frag(bp2 + kb * 512);
  #pragma unroll
  for (int q = 0; q < 16; ++q)    // q = c*4+jj -> global kb = c*16 + wave*4 + jj
    w3r[q] = ld_frag(bp3 + ((q >> 2) * 16 + wave * 4 + (q & 3)) * 512);

  // biases: fixed per lane
  const float bb1 = b1[n16 * 16 + llo];
  const float bb2 = b2[n16 * 16 + llo];
  const float bb3 = b3[gn * 16 + llo];

  // ---- init: y tiles from x, out[:,0,:], ubuf = bf16(y) for all GPG groups ----
  {
    int row = tid >> 4, c16 = tid & 15;
    int col = gn * 16 + c16;
    #pragma unroll
    for (int q = 0; q < GPG; ++q) {
      int b = (set * GPG + q) * M_ + row;
      float v = x[(size_t)b * (T_ * C_) + col];
      ytile[q][tid] = v;
      out[(size_t)b * (T_ * C_) + col] = v;
      st_coh16(&ubs[q][row * C_ + col], tobf(v));
    }
  }
  unsigned gen = 1;
  #pragma unroll
  for (int q = 0; q < GPG; ++q) bar_arrive(gf[q], gn, 1);   // u ready @ gen 1

  ull va[8], vb[8];
  #pragma unroll 1
  for (int t = 0; t < T_ - 1; ++t) {
    #pragma unroll 1
    for (int sub = 0; sub < 3; ++sub) {
      #pragma unroll 1
      for (int st = 0; st < 4; ++st) {
        // ======== layer 1 rotation: consume u@gen, produce h1@gen+1 ========
        #pragma unroll
        for (int q = 0; q < GPG; ++q) {
          bar_wait(gf[q], gen);
          issue_u(ubq[q], tid, va);
          bf16x8 w1f[16];                     // W1 streamed: L2-hit
          #pragma unroll
          for (int kb = 0; kb < 16; ++kb) w1f[kb] = ld_frag(bp1 + kb * 512);
          commit(atile[0], tid, va);
          LGKM0_BAR();
          f32x4 acc0 = {0.f, 0.f, 0.f, 0.f}, acc1 = {0.f, 0.f, 0.f, 0.f};
          const unsigned short* al = (const unsigned short*)atile[0] + llo * RSS1 + lhi * 8;
          #pragma unroll
          for (int jj = 0; jj < 8; ++jj) {
            acc0 = mfma16(lds_frag(al + (2 * jj) * 32),     w1f[2 * jj],     acc0);
            acc1 = mfma16(lds_frag(al + (2 * jj + 1) * 32), w1f[2 * jj + 1], acc1);
          }
          f32x4 a = acc0 + acc1;
          const int col = n16 * 16 + llo;
          #pragma unroll
          for (int r = 0; r < 4; ++r)
            st_coh16(&h1s[q][(lhi * 4 + r) * H_ + col], tobf(fast_tanh(a[r] + bb1)));
          bar_arrive(gf[q], gn, gen + 1);
        }
        ++gen;

        // ======== layer 2 rotation: consume h1@gen, produce h2@gen+1 ========
        #pragma unroll
        for (int q = 0; q < GPG; ++q) {
          bar_wait(gf[q], gen);
          f32x4 acc0 = {0.f, 0.f, 0.f, 0.f}, acc1 = {0.f, 0.f, 0.f, 0.f};
          issue_c(h1q[q],       tid, va);
          issue_c(h1q[q] + 128, tid, vb);      // 2-deep staging pipeline
          commit(atile[0], tid, va);
          LGKM0_BAR();
          issue_c(h1q[q] + 256, tid, va);
          L2CHUNK(0, 0);
          commit(atile[1], tid, vb);
          LGKM0_BAR();
          issue_c(h1q[q] + 384, tid, vb);
          L2CHUNK(1, 1);
          commit(atile[0], tid, va);
          LGKM0_BAR();
          L2CHUNK(2, 0);
          commit(atile[1], tid, vb);
          LGKM0_BAR();
          L2CHUNK(3, 1);
          f32x4 a = acc0 + acc1;
          const int col = n16 * 16 + llo;
          #pragma unroll
          for (int r = 0; r < 4; ++r)
            st_coh16(&h2s[q][(lhi * 4 + r) * H_ + col], tobf(fast_tanh(a[r] + bb2)));
          bar_arrive(gf[q], gn, gen + 1);
        }
        ++gen;

        // === layer 3 rotation: consume h2@gen, RK4, produce u@gen+1 ===
        #pragma unroll
        for (int q = 0; q < GPG; ++q) {
          bar_wait(gf[q], gen);
          f32x4 acc0 = {0.f, 0.f, 0.f, 0.f}, acc1 = {0.f, 0.f, 0.f, 0.f};
          issue_c(h2q[q],       tid, va);
          issue_c(h2q[q] + 128, tid, vb);
          commit(atile[0], tid, va);
          LGKM0_BAR();
          issue_c(h2q[q] + 256, tid, va);
          L3CHUNK(0, 0);
          commit(atile[1], tid, vb);
          LGKM0_BAR();
          issue_c(h2q[q] + 384, tid, vb);
          L3CHUNK(1, 1);
          commit(atile[0], tid, va);
          LGKM0_BAR();
          L3CHUNK(2, 0);
          commit(atile[1], tid, vb);
          LGKM0_BAR();
          L3CHUNK(3, 1);
          f32x4 a = acc0 + acc1;
          #pragma unroll
          for (int r = 0; r < 4; ++r) red[wave][(lhi * 4 + r) * 16 + llo] = a[r];
          __syncthreads();
          if (wave == 0) {
            const float dt = DT_F;
            #pragma unroll
            for (int r = 0; r < 4; ++r) {
              int row = lhi * 4 + r;
              int i = row * 16 + llo;
              float z = red[0][i] + red[1][i] + red[2][i] + red[3][i] + bb3;
              float yv = ytile[q][i];
              unsigned short* up = &ubs[q][row * C_ + gn * 16 + llo];
              if (st == 0)      { k1t[q][i] = z; st_coh16(up, tobf(yv + 0.5f * dt * z)); }
              else if (st == 1) { k2t[q][i] = z; st_coh16(up, tobf(yv + 0.5f * dt * z)); }
              else if (st == 2) { k3t[q][i] = z; st_coh16(up, tobf(yv + dt * z)); }
              else {
                float yn = yv + (dt * (1.0f / 6.0f)) *
                           (k1t[q][i] + 2.f * k2t[q][i] + 2.f * k3t[q][i] + z);
                ytile[q][i] = yn;
                st_coh16(up, tobf(yn));
                if (sub == 2)
                  out[(size_t)((set * GPG + q) * M_ + row) * (T_ * C_) +
                      (size_t)(t + 1) * C_ + gn * 16 + llo] = yn;
              }
            }
          }
          bar_arrive(gf[q], gn, gen + 1);
        }
        ++gen;
      }
    }
  }
}

// ---------------- host ----------------
extern "C" void kernel_launch(void* const* d_in, const int* in_sizes, int n_in,
                              void* d_out, int out_size, void* d_ws, size_t ws_size,
                              hipStream_t stream) {
  (void)in_sizes; (void)n_in; (void)out_size; (void)ws_size;
  const float* x  = (const float*)d_in[0];
  const float* W1 = (const float*)d_in[1];
  const float* b1 = (const float*)d_in[2];
  const float* W2 = (const float*)d_in[3];
  const float* b2 = (const float*)d_in[4];
  const float* W3 = (const float*)d_in[5];
  const float* b3 = (const float*)d_in[6];
  float* out = (float*)d_out;
  unsigned char* ws = (unsigned char*)d_ws;

  init_flags_k<<<16, 256, 0, stream>>>((unsigned*)(ws + OFF_FLAGS));
  // W1: K=512 (kblog=4), N=2048 ; W2: K=2048 (kblog=6), N=2048 ; W3: K=2048 (kblog=6), N=512
  swizzle_w_k<<<(C_ * H_) / 256, 256, 0, stream>>>(W1, (unsigned short*)(ws + OFF_W1P), H_, 4);
  swizzle_w_k<<<(H_ * H_) / 256, 256, 0, stream>>>(W2, (unsigned short*)(ws + OFF_W2P), H_, 6);
  swizzle_w_k<<<(H_ * C_) / 256, 256, 0, stream>>>(W3, (unsigned short*)(ws + OFF_W3P), C_, 6);

  ode_persist_k<<<NWG, NTHR, 0, stream>>>(x, b1, b2, b3, out, ws);
}

// Round 9
// 68068.951 us; speedup vs baseline: 3.2857x; 3.2857x over previous
//
#include <hip/hip_runtime.h>
#include <hip/hip_bf16.h>
#include <cstdint>

#define B_ 128
#define T_ 256
#define C_ 512
#define H_ 2048
#define NWG 256
#define NTHR 256
#define NGROUP 8
#define GSIZE 32        // WGs per row-group
#define M_ 16           // batch rows per group
#define FSTRIDE 16      // flag padding (dwords) -> 64 B per flag
#define RSU1 132        // atile row stride in ull
#define RSS1 528        // row stride in shorts
// DT = (1/(T-1))/N_SUB = 1/765
#define DT_F 0.0013071895424836601f
#define RETRY_CAP 64    // tag-poll rounds before per-wave flag rescue

typedef __bf16 bf16x8 __attribute__((ext_vector_type(8)));
typedef short s16x8 __attribute__((ext_vector_type(8)));
typedef float f32x4 __attribute__((ext_vector_type(4)));
typedef unsigned long long ull;

// ---------------- workspace layout (bytes) ----------------
// Tagged activation buffers: u32 word = (gen_tag<<16) | bf16raw, double-buffered
// by generation parity (depth-2 dataflow => WAR-safe without barriers).
enum : size_t {
  OFF_FLAGS = 0,                                     // 8*32*64B rescue flags (16 KB)
  OFF_W1P   = 32768,
  OFF_W2P   = OFF_W1P + (size_t)C_ * H_ * 2,         // 2 MB
  OFF_W3P   = OFF_W2P + (size_t)H_ * H_ * 2,         // 8 MB
  OFF_TU    = OFF_W3P + (size_t)H_ * C_ * 2,         // 8g*2par*16*512*4B  = 512 KB
  OFF_TH1   = OFF_TU  + (size_t)NGROUP * 2 * M_ * C_ * 4,   // 8*2*16*2048*4 = 2 MB
  OFF_TH2   = OFF_TH1 + (size_t)NGROUP * 2 * M_ * H_ * 4,   // 2 MB
  WS_END    = OFF_TH2 + (size_t)NGROUP * 2 * M_ * H_ * 4    // ~16.6 MB
};
#define NTAGU32 ((size_t)(WS_END - OFF_TU) / 4)

__device__ __forceinline__ bf16x8 ld_frag(const unsigned short* p) {   // weights
  s16x8 v = *reinterpret_cast<const s16x8*>(p);
  return __builtin_bit_cast(bf16x8, v);
}
__device__ __forceinline__ bf16x8 lds_frag(const unsigned short* p) {  // ds_read_b128
  s16x8 v = *reinterpret_cast<const s16x8*>(p);
  return __builtin_bit_cast(bf16x8, v);
}
__device__ __forceinline__ f32x4 mfma16(bf16x8 a, bf16x8 b, f32x4 c) {
  return __builtin_amdgcn_mfma_f32_16x16x32_bf16(a, b, c, 0, 0, 0);
}
__device__ __forceinline__ unsigned short tobf(float f) {
  return __builtin_bit_cast(unsigned short, (__bf16)f);
}
__device__ __forceinline__ float fast_tanh(float v) {
  float e = __expf(2.0f * v);
  return 1.0f - 2.0f / (e + 1.0f);
}
// tagged store: aligned dword store is single-copy atomic -> word self-validates
__device__ __forceinline__ void st_tag32(unsigned* p, unsigned short bf, unsigned tag) {
  __hip_atomic_store(p, (tag << 16) | (unsigned)bf, __ATOMIC_RELAXED,
                     __HIP_MEMORY_SCOPE_AGENT);
}
// pack 4 bf16 values out of two tagged ulls (4 u32 words, values in lo16)
__device__ __forceinline__ ull pack4(ull lo, ull hi) {
  return (lo & 0xFFFFull) | (((lo >> 32) & 0xFFFFull) << 16)
       | ((hi & 0xFFFFull) << 32) | (((hi >> 32) & 0xFFFFull) << 48);
}
__device__ __forceinline__ bool tagok(ull lo, ull hi, unsigned tag) {
  ull t = tag;
  return (((lo >> 16) & 0xFFFFull) == t) && ((lo >> 48) == t)
      && (((hi >> 16) & 0xFFFFull) == t) && ((hi >> 48) == t);
}

// drain own LDS ops, raw barrier (keeps vmem loads in flight) — r7-proven
#define LGKM0_BAR() do {                                   \
  asm volatile("s_waitcnt lgkmcnt(0)" ::: "memory");       \
  __builtin_amdgcn_s_barrier();                            \
} while (0)

// ---------------- prologue kernels ----------------
__global__ void init_ws_k(unsigned* flags, unsigned* tagged) {
  size_t i = (size_t)blockIdx.x * 256 + threadIdx.x;
  if (i < NGROUP * GSIZE * FSTRIDE) flags[i] = 0u;
  for (size_t k = i; k < NTAGU32; k += (size_t)gridDim.x * 256) tagged[k] = 0u;
}

// Pack W[K][N] fp32 -> bf16 in MFMA B-fragment order (validated rounds 1-4)
__global__ void swizzle_w_k(const float* __restrict__ W, unsigned short* __restrict__ Wp,
                            int N, int kblog) {
  int idx = blockIdx.x * 256 + threadIdx.x;
  int j = idx & 7;
  int l = (idx >> 3) & 63;
  int rem = idx >> 9;
  int kb = rem & ((1 << kblog) - 1);
  int nt = rem >> kblog;
  int k = kb * 32 + ((l >> 4) << 3) + j;
  int n = (nt << 4) + (l & 15);
  Wp[idx] = tobf(W[(size_t)k * N + n]);
}

// ---------------- rescue flags (producer side; off the serial path) ----------
__device__ __forceinline__ void bar_arrive(unsigned* gf, int gn, unsigned gen) {
  asm volatile("s_waitcnt vmcnt(0)" ::: "memory");   // tagged stores drained
  __syncthreads();                                   // all waves of this WG
  if (threadIdx.x == 0)
    __hip_atomic_store(&gf[gn * FSTRIDE], gen, __ATOMIC_RELAXED, __HIP_MEMORY_SCOPE_AGENT);
}

// ---------------- tagged staging ----------------
// 16 tagged ulls per thread per chunk (agent loads); rs = row stride in ulls
// (u: 256, h: 1024); b pre-offset by chunk (+c*256).
__device__ __forceinline__ void tload16(const ull* __restrict__ b, int tid, int rs,
                                        ull v[16]) {
  #pragma unroll
  for (int jj = 0; jj < 8; ++jj) {
    int i8 = jj * NTHR + tid, row = i8 >> 7, off = i8 & 127;
    size_t a = (size_t)row * rs + off * 2;
    v[2*jj]   = __hip_atomic_load(b + a,     __ATOMIC_RELAXED, __HIP_MEMORY_SCOPE_AGENT);
    v[2*jj+1] = __hip_atomic_load(b + a + 1, __ATOMIC_RELAXED, __HIP_MEMORY_SCOPE_AGENT);
  }
}
// verify tags; selectively reload mismatches; per-wave flag rescue on cap.
__device__ __forceinline__ void finish_t(const ull* __restrict__ b, int tid, int rs,
                                         unsigned tag, ull v[16], ull p[8],
                                         const unsigned* gfl, unsigned fgen) {
  unsigned bad = 0;
  #pragma unroll
  for (int jj = 0; jj < 8; ++jj) {
    p[jj] = pack4(v[2*jj], v[2*jj+1]);
    if (!tagok(v[2*jj], v[2*jj+1], tag)) bad |= 1u << jj;
  }
  int tries = 0;
  while (!__all(bad == 0)) {
    if (++tries > RETRY_CAP) {               // per-wave rescue: NO cross-wave sync
      int lane = threadIdx.x & 63;
      if (lane < GSIZE) {
        while (__hip_atomic_load(&gfl[lane * FSTRIDE], __ATOMIC_RELAXED,
                                 __HIP_MEMORY_SCOPE_AGENT) < fgen)
          __builtin_amdgcn_s_sleep(1);
      }
      tload16(b, tid, rs, v);                // flags passed => data visible
      #pragma unroll
      for (int jj = 0; jj < 8; ++jj) p[jj] = pack4(v[2*jj], v[2*jj+1]);
      return;
    }
    #pragma unroll
    for (int jj = 0; jj < 8; ++jj) {
      if (bad & (1u << jj)) {
        int i8 = jj * NTHR + tid, row = i8 >> 7, off = i8 & 127;
        size_t a = (size_t)row * rs + off * 2;
        ull lo = __hip_atomic_load(b + a,     __ATOMIC_RELAXED, __HIP_MEMORY_SCOPE_AGENT);
        ull hi = __hip_atomic_load(b + a + 1, __ATOMIC_RELAXED, __HIP_MEMORY_SCOPE_AGENT);
        if (tagok(lo, hi, tag)) { p[jj] = pack4(lo, hi); bad &= ~(1u << jj); }
      }
    }
  }
}
__device__ __forceinline__ void commit(ull* __restrict__ lds, int tid, const ull v[8]) {
  #pragma unroll
  for (int j = 0; j < 8; ++j) {
    int i = j * NTHR + tid;
    lds[(i >> 7) * RSU1 + (i & 127)] = v[j];
  }
}

// compile-time-indexed compute macros (keep w2r/w3r register-resident!)
#define L2CHUNK(c, buf) {                                                     \
  const unsigned short* al = (const unsigned short*)atile[buf] + llo * RSS1 + lhi * 8; \
  _Pragma("unroll")                                                           \
  for (int jj = 0; jj < 8; ++jj) {                                            \
    acc0 = mfma16(lds_frag(al + (2 * jj) * 32),     w2r[(c) * 16 + 2 * jj],     acc0); \
    acc1 = mfma16(lds_frag(al + (2 * jj + 1) * 32), w2r[(c) * 16 + 2 * jj + 1], acc1); \
  } }

#define L3CHUNK(c, buf) {                                                     \
  const unsigned short* al = (const unsigned short*)atile[buf] + llo * RSS1 + lhi * 8; \
  _Pragma("unroll")                                                           \
  for (int jj = 0; jj < 2; ++jj) {                                            \
    acc0 = mfma16(lds_frag(al + (wave * 4 + 2 * jj) * 32),     w3r[(c) * 4 + 2 * jj],     acc0); \
    acc1 = mfma16(lds_frag(al + (wave * 4 + 2 * jj + 1) * 32), w3r[(c) * 4 + 2 * jj + 1], acc1); \
  } }

// ---------------- persistent ODE kernel, tagged dataflow ----------------
// 8 groups x 32 WGs (baseline mapping). No consumer flag-waits: activations are
// self-validating (gen tag per dword); consumers poll data directly (1 RT).
// Producers post baseline flags off the serial path for the bounded rescue.
__global__ __launch_bounds__(NTHR, 1) void ode_persist_k(
    const float* __restrict__ x, const float* __restrict__ b1,
    const float* __restrict__ b2, const float* __restrict__ b3,
    float* __restrict__ out, unsigned char* __restrict__ ws) {
  const int wg = blockIdx.x, tid = threadIdx.x;
  const int g = wg >> 5, gn = wg & 31;
  const int wave = tid >> 6, lane = tid & 63;
  const int lhi = lane >> 4, llo = lane & 15;

  unsigned* gflags = (unsigned*)(ws + OFF_FLAGS) + g * GSIZE * FSTRIDE;
  const unsigned short* W1p = (const unsigned short*)(ws + OFF_W1P);
  const unsigned short* W2p = (const unsigned short*)(ws + OFF_W2P);
  const unsigned short* W3p = (const unsigned short*)(ws + OFF_W3P);

  // tagged buffers, parity 0/1 (named pointers: no runtime-indexed arrays)
  unsigned* tuw0 = (unsigned*)(ws + OFF_TU) + (size_t)g * 16384;
  unsigned* tuw1 = tuw0 + 8192;
  const ull* tur0 = (const ull*)tuw0;
  const ull* tur1 = (const ull*)tuw1;
  unsigned* h1w0 = (unsigned*)(ws + OFF_TH1) + (size_t)g * 65536;
  unsigned* h1w1 = h1w0 + 32768;
  const ull* h1r0 = (const ull*)h1w0;
  const ull* h1r1 = (const ull*)h1w1;
  unsigned* h2w0 = (unsigned*)(ws + OFF_TH2) + (size_t)g * 65536;
  unsigned* h2w1 = h2w0 + 32768;
  const ull* h2r0 = (const ull*)h2w0;
  const ull* h2r1 = (const ull*)h2w1;

  __shared__ alignas(16) ull atile[2][M_ * RSU1];   // 2 x 16.5 KB
  __shared__ float red[4][256];
  __shared__ float ytile[256], k1t[256], k2t[256], k3t[256];

  // weight bases (B-fragment layout)
  const int n16 = gn * 4 + wave;
  const unsigned short* bp1 = W1p + (size_t)n16 * 16 * 512 + lane * 8;
  const unsigned short* bp2 = W2p + (size_t)n16 * 64 * 512 + lane * 8;
  const unsigned short* bp3 = W3p + (size_t)gn  * 64 * 512 + lane * 8;

  // register-resident W2 / W3 slices (unified VGPR/AGPR file holds these)
  bf16x8 w2r[64], w3r[16];
  #pragma unroll
  for (int kb = 0; kb < 64; ++kb) w2r[kb] = ld_frag(bp2 + kb * 512);
  #pragma unroll
  for (int q = 0; q < 16; ++q)
    w3r[q] = ld_frag(bp3 + ((q >> 2) * 16 + wave * 4 + (q & 3)) * 512);

  const float bb1 = b1[n16 * 16 + llo];
  const float bb2 = b2[n16 * 16 + llo];
  const float bb3 = b3[gn * 16 + llo];

  // ---- init: y tile, out[:,0,:], tagged u (tag 1 -> parity 1) ----
  {
    int row = tid >> 4, c16 = tid & 15;
    int col = gn * 16 + c16;
    int b = g * M_ + row;
    float v = x[(size_t)b * (T_ * C_) + col];
    ytile[tid] = v;
    out[(size_t)b * (T_ * C_) + col] = v;
    st_tag32(&tuw1[row * 512 + col], tobf(v), 1u);
  }
  bar_arrive(gflags, gn, 1);          // rescue flag for u tag 1 (fgen = 3*1-2)

  ull v0[16], v1[16], p8[8];
  unsigned ev = 0;
  #pragma unroll 1
  for (int t = 0; t < T_ - 1; ++t) {
    #pragma unroll 1
    for (int sub = 0; sub < 3; ++sub) {
      #pragma unroll 1
      for (int st = 0; st < 4; ++st) {
        const unsigned tag = ev + 1;
        const int par = (int)(tag & 1u);
        const ull* tub = par ? tur1 : tur0;
        unsigned*  h1w = par ? h1w1 : h1w0;
        const ull* h1r = par ? h1r1 : h1r0;
        unsigned*  h2w = par ? h2w1 : h2w0;
        const ull* h2r = par ? h2r1 : h2r0;
        unsigned*  tun = par ? tuw0 : tuw1;     // u tag+1 -> opposite parity

        // ================= layer 1: u -> h1 =================
        {
          tload16(tub, tid, 256, v0);           // tag-poll round 1 in flight
          bf16x8 w1f[16];
          #pragma unroll
          for (int kb = 0; kb < 16; ++kb) w1f[kb] = ld_frag(bp1 + kb * 512);
          finish_t(tub, tid, 256, tag, v0, p8, gflags, 3 * tag - 2);
          commit(atile[0], tid, p8);
          LGKM0_BAR();
          f32x4 acc0 = {0.f, 0.f, 0.f, 0.f}, acc1 = {0.f, 0.f, 0.f, 0.f};
          const unsigned short* al = (const unsigned short*)atile[0] + llo * RSS1 + lhi * 8;
          #pragma unroll
          for (int jj = 0; jj < 8; ++jj) {
            acc0 = mfma16(lds_frag(al + (2 * jj) * 32),     w1f[2 * jj],     acc0);
            acc1 = mfma16(lds_frag(al + (2 * jj + 1) * 32), w1f[2 * jj + 1], acc1);
          }
          f32x4 a = acc0 + acc1;
          const int col = n16 * 16 + llo;
          #pragma unroll
          for (int r = 0; r < 4; ++r)
            st_tag32(&h1w[(lhi * 4 + r) * H_ + col], tobf(fast_tanh(a[r] + bb1)), tag);
        }
        bar_arrive(gflags, gn, 3 * tag - 1);    // rescue flag for h1@tag

        // ================= layer 2: h1 -> h2 =================
        {
          f32x4 acc0 = {0.f, 0.f, 0.f, 0.f}, acc1 = {0.f, 0.f, 0.f, 0.f};
          tload16(h1r,       tid, 1024, v0);
          tload16(h1r + 256, tid, 1024, v1);
          finish_t(h1r,       tid, 1024, tag, v0, p8, gflags, 3 * tag - 1);
          commit(atile[0], tid, p8);
          LGKM0_BAR();
          tload16(h1r + 512, tid, 1024, v0);
          L2CHUNK(0, 0);
          finish_t(h1r + 256, tid, 1024, tag, v1, p8, gflags, 3 * tag - 1);
          commit(atile[1], tid, p8);
          LGKM0_BAR();
          tload16(h1r + 768, tid, 1024, v1);
          L2CHUNK(1, 1);
          finish_t(h1r + 512, tid, 1024, tag, v0, p8, gflags, 3 * tag - 1);
          commit(atile[0], tid, p8);
          LGKM0_BAR();
          L2CHUNK(2, 0);
          finish_t(h1r + 768, tid, 1024, tag, v1, p8, gflags, 3 * tag - 1);
          commit(atile[1], tid, p8);
          LGKM0_BAR();
          L2CHUNK(3, 1);
          f32x4 a = acc0 + acc1;
          const int col = n16 * 16 + llo;
          #pragma unroll
          for (int r = 0; r < 4; ++r)
            st_tag32(&h2w[(lhi * 4 + r) * H_ + col], tobf(fast_tanh(a[r] + bb2)), tag);
        }
        bar_arrive(gflags, gn, 3 * tag);        // rescue flag for h2@tag

        // ====== layer 3: h2 -> z, RK4, tagged u@tag+1 ======
        {
          f32x4 acc0 = {0.f, 0.f, 0.f, 0.f}, acc1 = {0.f, 0.f, 0.f, 0.f};
          tload16(h2r,       tid, 1024, v0);
          tload16(h2r + 256, tid, 1024, v1);
          finish_t(h2r,       tid, 1024, tag, v0, p8, gflags, 3 * tag);
          commit(atile[0], tid, p8);
          LGKM0_BAR();
          tload16(h2r + 512, tid, 1024, v0);
          L3CHUNK(0, 0);
          finish_t(h2r + 256, tid, 1024, tag, v1, p8, gflags, 3 * tag);
          commit(atile[1], tid, p8);
          LGKM0_BAR();
          tload16(h2r + 768, tid, 1024, v1);
          L3CHUNK(1, 1);
          finish_t(h2r + 512, tid, 1024, tag, v0, p8, gflags, 3 * tag);
          commit(atile[0], tid, p8);
          LGKM0_BAR();
          L3CHUNK(2, 0);
          finish_t(h2r + 768, tid, 1024, tag, v1, p8, gflags, 3 * tag);
          commit(atile[1], tid, p8);
          LGKM0_BAR();
          L3CHUNK(3, 1);
          f32x4 a = acc0 + acc1;
          #pragma unroll
          for (int r = 0; r < 4; ++r) red[wave][(lhi * 4 + r) * 16 + llo] = a[r];
          __syncthreads();
          if (wave == 0) {
            const float dt = DT_F;
            #pragma unroll
            for (int r = 0; r < 4; ++r) {
              int row = lhi * 4 + r;
              int i = row * 16 + llo;
              float z = red[0][i] + red[1][i] + red[2][i] + red[3][i] + bb3;
              float yv = ytile[i];
              unsigned* up = &tun[row * 512 + gn * 16 + llo];
              if (st == 0)      { k1t[i] = z; st_tag32(up, tobf(yv + 0.5f * dt * z), tag + 1); }
              else if (st == 1) { k2t[i] = z; st_tag32(up, tobf(yv + 0.5f * dt * z), tag + 1); }
              else if (st == 2) { k3t[i] = z; st_tag32(up, tobf(yv + dt * z), tag + 1); }
              else {
                float yn = yv + (dt * (1.0f / 6.0f)) * (k1t[i] + 2.f * k2t[i] + 2.f * k3t[i] + z);
                ytile[i] = yn;
                st_tag32(up, tobf(yn), tag + 1);
                if (sub == 2)
                  out[(size_t)(g * M_ + row) * (T_ * C_) + (size_t)(t + 1) * C_ + gn * 16 + llo] = yn;
              }
            }
          }
        }
        bar_arrive(gflags, gn, 3 * tag + 1);    // = 3*(tag+1)-2: rescue for u@tag+1
        ++ev;
      }
    }
  }
}

// ---------------- host ----------------
extern "C" void kernel_launch(void* const* d_in, const int* in_sizes, int n_in,
                              void* d_out, int out_size, void* d_ws, size_t ws_size,
                              hipStream_t stream) {
  (void)in_sizes; (void)n_in; (void)out_size; (void)ws_size;
  const float* x  = (const float*)d_in[0];
  const float* W1 = (const float*)d_in[1];
  const float* b1 = (const float*)d_in[2];
  const float* W2 = (const float*)d_in[3];
  const float* b2 = (const float*)d_in[4];
  const float* W3 = (const float*)d_in[5];
  const float* b3 = (const float*)d_in[6];
  float* out = (float*)d_out;
  unsigned char* ws = (unsigned char*)d_ws;

  // zero flags + ALL tag words (stale tags from a previous launch would falsely match)
  init_ws_k<<<1024, 256, 0, stream>>>((unsigned*)(ws + OFF_FLAGS),
                                      (unsigned*)(ws + OFF_TU));
  swizzle_w_k<<<(C_ * H_) / 256, 256, 0, stream>>>(W1, (unsigned short*)(ws + OFF_W1P), H_, 4);
  swizzle_w_k<<<(H_ * H_) / 256, 256, 0, stream>>>(W2, (unsigned short*)(ws + OFF_W2P), H_, 6);
  swizzle_w_k<<<(H_ * C_) / 256, 256, 0, stream>>>(W3, (unsigned short*)(ws + OFF_W3P), C_, 6);

  ode_persist_k<<<NWG, NTHR, 0, stream>>>(x, b1, b2, b3, out, ws);
}